// Round 11
// baseline (361.356 us; speedup 1.0000x reference)
//
#include <hip/hip_runtime.h>

#define DEV __device__ __forceinline__

typedef __attribute__((ext_vector_type(8))) short short8;
typedef __bf16 bf16x8 __attribute__((ext_vector_type(8)));
typedef __attribute__((ext_vector_type(4))) float f32x4;
typedef __attribute__((ext_vector_type(4))) unsigned uint4v;

constexpr int NB = 16;
constexpr int NN = 64;
constexpr int ND = 512;
constexpr int NH = 8;

DEV float b2f(unsigned short h) { return __uint_as_float(((unsigned)h) << 16); }
DEV unsigned short f2b(float f) {
    unsigned u = __float_as_uint(f);
    return (unsigned short)((u + 0x7fffu + ((u >> 16) & 1u)) >> 16);
}
// mish(x) = x*(t^2+2t)/(t^2+2t+2), t=e^x; x>15 -> x
DEV float mish_fast(float x) {
    float t = __expf(x);
    float w = t * (t + 2.0f);
    float r = x * w * __builtin_amdgcn_rcpf(w + 2.0f);
    return (x > 15.0f) ? x : r;
}
DEV void gload16(const unsigned short* g, unsigned short* lds) {
    __builtin_amdgcn_global_load_lds((const __attribute__((address_space(1))) void*)g,
                                     (__attribute__((address_space(3))) void*)lds,
                                     16, 0, 0);
}

#define WAITV(N) asm volatile("s_waitcnt vmcnt(" #N ")" ::: "memory")
#define WAITL()  asm volatile("s_waitcnt lgkmcnt(0)" ::: "memory")

// ---------------------------------------------------------------------------
__global__ __launch_bounds__(64)
void probe_dtype(const unsigned* __restrict__ adj, int* __restrict__ flag)
{
    int t = threadIdx.x;
    int c = 0;
#pragma unroll
    for (int i = 0; i < 4; ++i) c += (int)((adj[t * 4 + i] >> 15) & 1u);
    for (int off = 32; off; off >>= 1) c += __shfl_xor(c, off);
    if (t == 0) flag[0] = (c > 32) ? 1 : 0;
}

// ---------------------------------------------------------------------------
__global__ __launch_bounds__(256)
void wtrans(const void* W0, const void* W1, const void* W2, const void* W3,
            const void* W4, unsigned short* __restrict__ out,
            const int* __restrict__ flag)
{
    const void* W = (blockIdx.z == 0) ? W0 : (blockIdx.z == 1) ? W1 :
                    (blockIdx.z == 2) ? W2 : (blockIdx.z == 3) ? W3 : W4;
    const int f32 = flag[0];
    unsigned short* o = out + (size_t)blockIdx.z * 262144;
    __shared__ unsigned short tile[64][65];
    const int t = threadIdx.x;
    const int k0 = blockIdx.x * 64, c0 = blockIdx.y * 64;
#pragma unroll
    for (int rep = 0; rep < 16; ++rep) {
        int idx = rep * 256 + t;
        int r = idx >> 6, c = idx & 63;
        size_t gi = (size_t)(k0 + r) * 512 + c0 + c;
        float v = f32 ? ((const float*)W)[gi]
                      : b2f(((const unsigned short*)W)[gi]);
        tile[r][c] = f2b(v);
    }
    __syncthreads();
#pragma unroll
    for (int rep = 0; rep < 16; ++rep) {
        int idx = rep * 256 + t;
        int cc = idx >> 6, kk = idx & 63;
        o[(size_t)(c0 + cc) * 512 + k0 + kk] = tile[kk][cc];
    }
}

// ---------------------------------------------------------------------------
// GEMM v8: out[64 x 512 per block] = f( A[64 x 512] @ W + bias )
// BARRIER-FREE K-loop. 256 thr / 4 waves; wave = 64 rows x 128 cols
// (4x8 frags, acc = 128 VGPR).
// A: direct global->register loads in MFMA fragment layout (lane (rA,p)
//    loads A[row][s*32+p*8 .. +8]); 4 waves read identical addresses -> L1.
//    f32->bf16 / msg-scale applied in registers. NO LDS for A.
// B: global_load_lds ping-pong, WAVE-PRIVATE 128-col region -> ordering by
//    the wave's own vmcnt only. Per step: issueB(s+1) then WAITV(8)
//    (drains B(s)+A(s), leaves exactly B(s+1) in flight - count-exact for
//    all AMODEs), mkAf (cvt/scale), loadA(s+1), 8 ds_read_b128, lgkmcnt(0),
//    32 MFMA. No s_barrier anywhere in the loop.
// One s_barrier before the epilogue: in-place safety (a fast wave's f32
// writes would clobber k-slices slower waves still read).
// LDS: Bb[2][512][32]sh = 64 KB -> 2 blocks/CU.
// Bb slot: k-granule p of col c at slot p^((c>>1)&3) (bank-audited, r10: 0).
// AMODE: 0 = raw input (f32 per flag / bf16), 1 = bf16, 2 = bf16 * msg.
// ---------------------------------------------------------------------------
template<int AMODE, bool AF32, bool MISH, bool OUTF32>
DEV void g8_body(const char* Ap, long long apitch_elts,
                 const unsigned short* Btp,
                 const void* biasp, const float* msg,
                 void* outp, long long opitch, int f32g,
                 long long row0, unsigned short (*Bb)[512][32])
{
    const int t = threadIdx.x;
    const int lane = t & 63;
    const int wv = t >> 6;
    const int rA = lane & 15;
    const int p  = lane >> 4;                        // k-granule 0..3
    const int sl = (p ^ ((rA >> 1) & 3)) * 8;        // B frag-read slot
    const int bcf = lane >> 2;
    const int bg  = (lane & 3) ^ ((lane >> 3) & 3);

    constexpr int ESZ = AF32 ? 4 : 2;
    // per-frag A base pointers (row + k-granule offset)
    const char* aB[4];
#pragma unroll
    for (int mi = 0; mi < 4; ++mi) {
        long long gr = row0 + mi * 16 + rA;
        aB[mi] = Ap + (gr * apitch_elts + p * 8) * ESZ;
    }
    const float* mb[4];
    if (AMODE == 2) {
#pragma unroll
        for (int mi = 0; mi < 4; ++mi) {
            long long gr = row0 + mi * 16 + rA;
            int b = (int)(gr >> 12), m = (int)(gr >> 6) & 63, n = (int)gr & 63;
            mb[mi] = msg + (((long long)b * 8) * 64 + m) * 64 + n;
        }
    }

    f32x4 acc[4][8];
#pragma unroll
    for (int mi = 0; mi < 4; ++mi)
#pragma unroll
        for (int ni = 0; ni < 8; ++ni) acc[mi][ni] = f32x4{0.f, 0.f, 0.f, 0.f};

    uint4v rf[4][2];     // AF32 raw f32 (32 VGPR)
    short8 rh[4];        // bf16 raw (16 VGPR)
    float  msv[4];

    auto loadA = [&](int s) {
#pragma unroll
        for (int mi = 0; mi < 4; ++mi) {
            if (AF32) {
                rf[mi][0] = *reinterpret_cast<const uint4v*>(aB[mi] + s * 128);
                rf[mi][1] = *reinterpret_cast<const uint4v*>(aB[mi] + s * 128 + 16);
            } else {
                rh[mi] = *reinterpret_cast<const short8*>(aB[mi] + s * 64);
            }
        }
        if (AMODE == 2) {
#pragma unroll
            for (int mi = 0; mi < 4; ++mi) msv[mi] = mb[mi][(s >> 1) * 4096];
        }
    };
    auto mkAf = [&](bf16x8* af) {
#pragma unroll
        for (int mi = 0; mi < 4; ++mi) {
            short8 sv;
            if (AF32) {
#pragma unroll
                for (int j = 0; j < 4; ++j) {
                    sv[j]     = (short)f2b(__uint_as_float(rf[mi][0][j]));
                    sv[j + 4] = (short)f2b(__uint_as_float(rf[mi][1][j]));
                }
            } else if (AMODE == 2) {
#pragma unroll
                for (int j = 0; j < 8; ++j)
                    sv[j] = (short)f2b(b2f((unsigned short)rh[mi][j]) * msv[mi]);
            } else {
                sv = rh[mi];
            }
            af[mi] = *reinterpret_cast<bf16x8*>(&sv);
        }
    };
    auto issueB = [&](int s) {
#pragma unroll
        for (int j = 0; j < 8; ++j) {
            int colb = wv * 128 + j * 16;
            const unsigned short* src =
                Btp + (size_t)(colb + bcf) * 512 + s * 32 + bg * 8;
            gload16(src, &Bb[s & 1][colb][0]);
        }
    };

    // ---- prologue (no barrier) ----
    issueB(0);
    loadA(0);

    // ---- 16 K-steps, barrier-free ----
#pragma unroll
    for (int s = 0; s < 16; ++s) {
        if (s < 15) issueB(s + 1);
        // drain B(s)+A(s); leave exactly B(s+1)'s 8 in flight
        if (s < 15) WAITV(8); else WAITV(0);
        bf16x8 af[4];
        mkAf(af);                      // consumes A(s) regs
        if (s < 15) loadA(s + 1);      // reissue into same regs (WAR-ordered)
        bf16x8 bf[8];
#pragma unroll
        for (int ni = 0; ni < 8; ++ni)
            bf[ni] = *reinterpret_cast<const bf16x8*>(
                &Bb[s & 1][wv * 128 + ni * 16 + rA][sl]);
        WAITL();
        __builtin_amdgcn_sched_barrier(0);
        __builtin_amdgcn_s_setprio(1);
#pragma unroll
        for (int mi = 0; mi < 4; ++mi)
#pragma unroll
            for (int ni = 0; ni < 8; ++ni)
                acc[mi][ni] = __builtin_amdgcn_mfma_f32_16x16x32_bf16(
                    af[mi], bf[ni], acc[mi][ni], 0, 0, 0);
        __builtin_amdgcn_s_setprio(0);
    }

    // in-place safety: all waves' A reads complete (each wave drained its own
    // vmem at s=15) before any wave writes output bytes that alias A
    __builtin_amdgcn_s_barrier();

    // ---- epilogue: C/D layout col=lane&15, row=(lane>>4)*4+rr ----
    const int orow_q = (lane >> 4) * 4;
#pragma unroll
    for (int mi = 0; mi < 4; ++mi) {
#pragma unroll
        for (int ni = 0; ni < 8; ++ni) {
            int col = wv * 128 + ni * 16 + rA;
            float bz = f32g ? ((const float*)biasp)[col]
                            : b2f(((const unsigned short*)biasp)[col]);
            long long rbase = row0 + mi * 16 + orow_q;
#pragma unroll
            for (int rr = 0; rr < 4; ++rr) {
                float v = acc[mi][ni][rr] + bz;
                if (MISH) v = mish_fast(v);
                long long oi = (rbase + rr) * opitch + col;
                if (OUTF32) ((float*)outp)[oi] = v;
                else        ((unsigned short*)outp)[oi] = f2b(v);
            }
        }
    }
}

template<int AMODE, bool MISH, bool OUTF32>
__global__ __launch_bounds__(256, 2)
void gemm8(const void* A, long long apitch,
           const unsigned short* __restrict__ Bt,
           const void* __restrict__ bias_raw,
           const float* __restrict__ msg,
           void* out, long long opitch,
           const int* __restrict__ flag,
           const void* A2, const unsigned short* Bt2,
           const void* bias2, void* out2)
{
    __shared__ alignas(16) unsigned short Bb[2][512][32];   // 64 KB
    const int f32g = flag[0];

    long long row0;
    const void* Ap = A; const unsigned short* Btp = Bt;
    const void* biasp = bias_raw; void* outp = out;
    if (A2 != nullptr && (int)blockIdx.x >= (int)(gridDim.x >> 1)) {
        Ap = A2; Btp = Bt2; biasp = bias2; outp = out2;
        row0 = (long long)(blockIdx.x - (gridDim.x >> 1)) * 64;
    } else {
        row0 = (long long)blockIdx.x * 64;
    }

    if (AMODE == 0 && f32g) {
        g8_body<0, true, MISH, OUTF32>((const char*)Ap, apitch, Btp, biasp,
                                       msg, outp, opitch, f32g, row0, Bb);
    } else {
        g8_body<AMODE, false, MISH, OUTF32>((const char*)Ap, apitch, Btp, biasp,
                                            msg, outp, opitch, f32g, row0, Bb);
    }
}

// ---------------------------------------------------------------------------
// Pass A: raw scores, kp read EXACTLY ONCE (verified rounds 6-10).
// ---------------------------------------------------------------------------
__global__ __launch_bounds__(256)
void score_kernel(const unsigned short* __restrict__ q,
                  const unsigned short* __restrict__ kp,
                  float* __restrict__ outS,
                  float* __restrict__ inS)
{
    const int bid = blockIdx.x;            // 512 blocks
    const int b  = bid >> 5;
    const int i0 = ((bid >> 2) & 7) * 8;
    const int j0 = (bid & 3) * 16;
    const int t = threadIdx.x, lane = t & 63, wv = t >> 6;

    __shared__ alignas(16) unsigned short qs[24][512];
    __shared__ float souts[8][16][8];
    __shared__ float sins[16][8][8];

#pragma unroll
    for (int r8 = 0; r8 < 6; ++r8) {
        int r = wv * 6 + r8;
        int grow = (r < 8) ? (i0 + r) : (j0 + r - 8);
        gload16(q + ((long long)(b * 64 + grow)) * 512 + lane * 8, &qs[r][0]);
    }
    __syncthreads();

    for (int batch = 0; batch < 4; ++batch) {
        const int rbase = wv * 32 + batch * 8;
        short8 kv[8];
#pragma unroll
        for (int u = 0; u < 8; ++u) {
            int r = rbase + u;
            int ii = r >> 4, jj = r & 15;
            kv[u] = *reinterpret_cast<const short8*>(
                kp + ((long long)((b * 64 + i0 + ii) * 64) + j0 + jj) * 1024 + lane * 8);
        }
#pragma unroll
        for (int u = 0; u < 8; ++u) {
            int r = rbase + u;
            int ii = r >> 4, jj = r & 15;
            short8 qi = *reinterpret_cast<const short8*>(&qs[ii][lane * 8]);
            short8 qj = *reinterpret_cast<const short8*>(&qs[8 + jj][lane * 8]);
            float so = 0.f, si = 0.f;
#pragma unroll
            for (int e = 0; e < 8; ++e) {
                float kf = b2f((unsigned short)kv[u][e]);
                so += kf * b2f((unsigned short)qi[e]);
                si += kf * b2f((unsigned short)qj[e]);
            }
#pragma unroll
            for (int off = 1; off < 8; off <<= 1) {
                so += __shfl_xor(so, off);
                si += __shfl_xor(si, off);
            }
            if ((lane & 7) == 0) {
                souts[ii][jj][lane >> 3] = so * 0.125f;
                sins[jj][ii][lane >> 3]  = si * 0.125f;
            }
        }
    }
    __syncthreads();

    {
        int h  = t >> 5;
        int ii = (t >> 2) & 7;
        int qq = t & 3;
        f32x4 v;
#pragma unroll
        for (int e = 0; e < 4; ++e) v[e] = souts[ii][qq * 4 + e][h];
        *reinterpret_cast<f32x4*>(
            &outS[(((long long)(b * 8 + h) * 64) + i0 + ii) * 64 + j0 + qq * 4]) = v;
    }
    {
        int h  = t >> 5;
        int jj = (t >> 1) & 15;
        int hf = t & 1;
        f32x4 v;
#pragma unroll
        for (int e = 0; e < 4; ++e) v[e] = sins[jj][hf * 4 + e][h];
        *reinterpret_cast<f32x4*>(
            &inS[(((long long)(b * 8 + h) * 64) + j0 + jj) * 64 + i0 + hf * 4]) = v;
    }
}

// ---------------------------------------------------------------------------
__global__ __launch_bounds__(256)
void softmax_combine(float* __restrict__ outS, const float* __restrict__ inS)
{
    const long long row = (long long)blockIdx.x * 4 + (threadIdx.x >> 6);
    const int l = threadIdx.x & 63;
    const int x = (int)(row & 63);
    float so = outS[row * 64 + l];
    float si = inS[row * 64 + l];
    float mo = so, mi = si;
    for (int off = 32; off; off >>= 1) {
        mo = fmaxf(mo, __shfl_xor(mo, off));
        mi = fmaxf(mi, __shfl_xor(mi, off));
    }
    float eo = __expf(so - mo), ei = __expf(si - mi);
    float zo = eo, zi = ei;
    for (int off = 32; off; off >>= 1) {
        zo += __shfl_xor(zo, off);
        zi += __shfl_xor(zi, off);
    }
    float ao = eo / zo, ai = ei / zi;
    outS[row * 64 + l] = (l == x) ? ai : (ao + ai);
}

// ---------------------------------------------------------------------------
__global__ __launch_bounds__(512)
void nh_kernel(const float* __restrict__ msg,
               const unsigned short* __restrict__ v,
               unsigned short* __restrict__ nh)
{
    const int bm = blockIdx.x;
    const int b = bm >> 6, m = bm & 63;
    const int t = threadIdx.x;
    __shared__ float ms2[8 * 64];
    ms2[t] = msg[((long long)b * 8 + (t >> 6)) * 4096 + m * 64 + (t & 63)];
    __syncthreads();
    const float* mrow = &ms2[(t >> 6) * 64];
    float acc = 0.f;
#pragma unroll 8
    for (int n = 0; n < 64; ++n)
        acc += mrow[n] * b2f(v[((long long)b * 64 + n) * 512 + t]);
    nh[(long long)bm * 1024 + t] = f2b(acc);
}

// ---------------------------------------------------------------------------
extern "C" void kernel_launch(void* const* d_in, const int* in_sizes, int n_in,
                              void* d_out, int out_size, void* d_ws, size_t ws_size,
                              hipStream_t stream)
{
    const void* qn = d_in[0];
    const void* vn = d_in[1];
    const void* ke = d_in[2];
    const unsigned* adj = (const unsigned*)d_in[3];
    const void* Wq = d_in[4];  const void* bq = d_in[5];
    const void* Wk = d_in[6];  const void* bk = d_in[7];
    const void* Wv = d_in[8];  const void* bv = d_in[9];
    const void* Wn = d_in[10]; const void* bn = d_in[11];
    const void* We = d_in[12]; const void* be = d_in[13];

    float* out_node = (float*)d_out;                       // 16*64*512 f32 (2 MB)
    float* out_edge = out_node + (size_t)NB * NN * ND;     // 16*64*64*512 f32
    unsigned short* kp = (unsigned short*)out_edge;        // bf16, pitch 1024 shorts
    unsigned short* nh = (unsigned short*)out_node;        // bf16, pitch 1024 shorts
    float* inS = out_node;  // in-scores scratch (2 MB) — dead before nh_kernel

    char* wsb = (char*)d_ws;
    int* flag = (int*)wsb;
    unsigned short* Wt  = (unsigned short*)(wsb + 16);     // 5 x 512 KB
    unsigned short* Wqt = Wt + 0 * 262144;
    unsigned short* Wkt = Wt + 1 * 262144;
    unsigned short* Wvt = Wt + 2 * 262144;
    unsigned short* Wnt = Wt + 3 * 262144;
    unsigned short* Wet = Wt + 4 * 262144;
    unsigned short* q_ws = Wt + 5 * 262144;                // 1 MB bf16
    unsigned short* v_ws = q_ws + 524288;                  // 1 MB bf16
    float* msg = (float*)(v_ws + 524288);                  // 2 MB f32
    // ws total ~6.5 MB

    probe_dtype<<<1, 64, 0, stream>>>(adj, flag);
    wtrans<<<dim3(8, 8, 5), 256, 0, stream>>>(Wq, Wk, Wv, Wn, We, Wt, flag);
    // q + v projections merged (f32 A): blocks 0-15 -> q, 16-31 -> v
    gemm8<0, false, false><<<32, 256, 0, stream>>>(
        qn, 512, Wqt, bq, nullptr, q_ws, 512, flag, vn, Wvt, bv, v_ws);
    // k projection -> strided bf16 inside the edge f32 output region
    gemm8<0, false, false><<<1024, 256, 0, stream>>>(
        ke, 512, Wkt, bk, nullptr, kp, 1024, flag, nullptr, nullptr, nullptr, nullptr);
    // message: raw scores (kp read once) + softmax/combine
    score_kernel<<<512, 256, 0, stream>>>(q_ws, kp, msg, inS);
    softmax_combine<<<2048, 256, 0, stream>>>(msg, inS);
    // node path
    nh_kernel<<<NB * NN, 512, 0, stream>>>(msg, v_ws, nh);
    gemm8<1, true, true><<<16, 256, 0, stream>>>(
        nh, 1024, Wnt, bn, nullptr, out_node, 512, flag, nullptr, nullptr, nullptr, nullptr);
    // edge path: msg-scaling fused into A-fragments; in-place
    gemm8<2, true, true><<<1024, 256, 0, stream>>>(
        kp, 1024, Wet, be, msg, out_edge, 512, flag, nullptr, nullptr, nullptr, nullptr);
}

// Round 12
// 260.183 us; speedup vs baseline: 1.3889x; 1.3889x over previous
//
#include <hip/hip_runtime.h>

#define DEV __device__ __forceinline__

typedef __attribute__((ext_vector_type(8))) short short8;
typedef __bf16 bf16x8 __attribute__((ext_vector_type(8)));
typedef __attribute__((ext_vector_type(4))) float f32x4;
typedef __attribute__((ext_vector_type(2))) unsigned uint2v;
typedef __attribute__((ext_vector_type(4))) unsigned uint4v;

constexpr int NB = 16;
constexpr int NN = 64;
constexpr int ND = 512;
constexpr int NH = 8;

DEV float b2f(unsigned short h) { return __uint_as_float(((unsigned)h) << 16); }
DEV unsigned short f2b(float f) {
    unsigned u = __float_as_uint(f);
    return (unsigned short)((u + 0x7fffu + ((u >> 16) & 1u)) >> 16);
}
// mish(x) = x*(t^2+2t)/(t^2+2t+2), t=e^x; x>15 -> x
DEV float mish_fast(float x) {
    float t = __expf(x);
    float w = t * (t + 2.0f);
    float r = x * w * __builtin_amdgcn_rcpf(w + 2.0f);
    return (x > 15.0f) ? x : r;
}
DEV void gload16(const unsigned short* g, unsigned short* lds) {
    __builtin_amdgcn_global_load_lds((const __attribute__((address_space(1))) void*)g,
                                     (__attribute__((address_space(3))) void*)lds,
                                     16, 0, 0);
}

#define WAITV(N) asm volatile("s_waitcnt vmcnt(" #N ")" ::: "memory")
#define WAITL()  asm volatile("s_waitcnt lgkmcnt(0)" ::: "memory")

// ---------------------------------------------------------------------------
__global__ __launch_bounds__(64)
void probe_dtype(const unsigned* __restrict__ adj, int* __restrict__ flag)
{
    int t = threadIdx.x;
    int c = 0;
#pragma unroll
    for (int i = 0; i < 4; ++i) c += (int)((adj[t * 4 + i] >> 15) & 1u);
    for (int off = 32; off; off >>= 1) c += __shfl_xor(c, off);
    if (t == 0) flag[0] = (c > 32) ? 1 : 0;
}

// ---------------------------------------------------------------------------
__global__ __launch_bounds__(256)
void wtrans(const void* W0, const void* W1, const void* W2, const void* W3,
            const void* W4, unsigned short* __restrict__ out,
            const int* __restrict__ flag)
{
    const void* W = (blockIdx.z == 0) ? W0 : (blockIdx.z == 1) ? W1 :
                    (blockIdx.z == 2) ? W2 : (blockIdx.z == 3) ? W3 : W4;
    const int f32 = flag[0];
    unsigned short* o = out + (size_t)blockIdx.z * 262144;
    __shared__ unsigned short tile[64][65];
    const int t = threadIdx.x;
    const int k0 = blockIdx.x * 64, c0 = blockIdx.y * 64;
#pragma unroll
    for (int rep = 0; rep < 16; ++rep) {
        int idx = rep * 256 + t;
        int r = idx >> 6, c = idx & 63;
        size_t gi = (size_t)(k0 + r) * 512 + c0 + c;
        float v = f32 ? ((const float*)W)[gi]
                      : b2f(((const unsigned short*)W)[gi]);
        tile[r][c] = f2b(v);
    }
    __syncthreads();
#pragma unroll
    for (int rep = 0; rep < 16; ++rep) {
        int idx = rep * 256 + t;
        int cc = idx >> 6, kk = idx & 63;
        o[(size_t)(c0 + cc) * 512 + k0 + kk] = tile[kk][cc];
    }
}

// ---------------------------------------------------------------------------
// GEMM v9: out[64 x 512 per block] = f( A[64 x 512] @ W + bias )
// OCCUPANCY-FIRST (m97 regime): 512 thr / 8 waves, wave tile 64x64
// (4x4 frags, acc = 64 VGPR; total ~120 <= 128) -> launch_bounds(512,4):
// 4 waves/SIMD; LDS 72 KB -> 2 blocks/CU -> 16 waves/CU.
// Per step s (one barrier, exact vmcnt for all AMODEs; A issued before B):
//   loadA(s+1) regs (1-2 loads/thread); issueB(s+1) (4 wave-private gload16)
//   8 frag ds_reads; lgkmcnt(0); 16 MFMA (setprio)
//   WAITV(4): A(s+1) regs landed, B(s+1) still in flight
//   writeA(s+1) (cvt/scale + 8B ds_write); WAITL; WAITV(0); s_barrier
// LDS layouts (bank-audited in r10, measured 0 conflicts):
//   Ab[2][64][32]sh:  granule g of row r at slot g^((r>>1)&3)
//   Bb[2][512][32]sh: k-granule p of col c at slot p^((c>>1)&3)
// AMODE: 0 = raw input (f32 per flag / bf16), 1 = bf16, 2 = bf16 * msg.
// In-place safe: all global A reads drained by s=14's vmcnt (before the last
// barrier); epilogue writes only after; blocks own disjoint 64-row ranges.
// ---------------------------------------------------------------------------
template<int AMODE, bool MISH, bool OUTF32>
__global__ __launch_bounds__(512, 4)
void gemm9(const void* A, long long apitch,
           const unsigned short* __restrict__ Bt,
           const void* __restrict__ bias_raw,
           const float* __restrict__ msg,
           void* out, long long opitch,
           const int* __restrict__ flag,
           const void* A2, const unsigned short* Bt2,
           const void* bias2, void* out2)
{
    __shared__ alignas(16) unsigned short Ab[2][64][32];    //  8 KB
    __shared__ alignas(16) unsigned short Bb[2][512][32];   // 64 KB
    const int f32g = flag[0];
    const int t = threadIdx.x;
    const int lane = t & 63;
    const int wv = t >> 6;           // 0..7 = 64-col panel

    long long row0;
    const void* Ap = A; const unsigned short* Btp = Bt;
    const void* biasp = bias_raw; void* outp = out;
    if (A2 != nullptr && (int)blockIdx.x >= (int)(gridDim.x >> 1)) {
        Ap = A2; Btp = Bt2; biasp = bias2; outp = out2;
        row0 = (long long)(blockIdx.x - (gridDim.x >> 1)) * 64;
    } else {
        row0 = (long long)blockIdx.x * 64;
    }

    const int rA = lane & 15;
    const int p  = lane >> 4;                       // k-granule 0..3
    const int sl = (p ^ ((rA >> 1) & 3)) * 8;       // frag-read slot (shorts)
    // A staging: thread t -> row 0..63, 4-element chunk 0..7
    const int arow = t >> 3;
    const int aq   = t & 7;
    const long long grA = row0 + arow;
    // ds_write slot (shorts): granule (aq>>1) swizzled + 4-short half
    const int awr_sh = (((aq >> 1) ^ ((arow >> 1) & 3)) << 3) + ((aq & 1) << 2);
    // B staging lane constants
    const int bcf = lane >> 2;                      // col fine 0..15
    const int bg  = (lane & 3) ^ ((lane >> 3) & 3); // pre-swizzled src granule

    const float* mptr = nullptr;
    if (AMODE == 2) {
        int b = (int)(grA >> 12), m = (int)(grA >> 6) & 63, n = (int)grA & 63;
        mptr = msg + (((long long)b * 8) * 64 + m) * 64 + n;   // + (s>>1)*4096
    }

    f32x4 acc[4][4];
#pragma unroll
    for (int mi = 0; mi < 4; ++mi)
#pragma unroll
        for (int ni = 0; ni < 4; ++ni) acc[mi][ni] = f32x4{0.f, 0.f, 0.f, 0.f};

    // ---- staging helpers (s = K-step 0..15) ----
    uint4v rf;           // AMODE0 f32: 4 floats (16 B)
    uint2v rh;           // bf16: 4 shorts (8 B)
    float  msv;
    auto loadA = [&](int s) {
        if (AMODE == 0 && f32g) {
            rf = *reinterpret_cast<const uint4v*>(
                (const float*)Ap + grA * apitch + s * 32 + aq * 4);
        } else {
            rh = *reinterpret_cast<const uint2v*>(
                (const unsigned short*)Ap + grA * apitch + s * 32 + aq * 4);
            if (AMODE == 2) msv = mptr[(s >> 1) * 4096];
        }
    };
    auto writeA = [&](int s) {
        unsigned short h[4];
        if (AMODE == 0 && f32g) {
#pragma unroll
            for (int j = 0; j < 4; ++j) h[j] = f2b(__uint_as_float(rf[j]));
        } else {
            h[0] = (unsigned short)(rh[0] & 0xffff);
            h[1] = (unsigned short)(rh[0] >> 16);
            h[2] = (unsigned short)(rh[1] & 0xffff);
            h[3] = (unsigned short)(rh[1] >> 16);
            if (AMODE == 2) {
#pragma unroll
                for (int j = 0; j < 4; ++j) h[j] = f2b(b2f(h[j]) * msv);
            }
        }
        uint2v w;
        w[0] = (unsigned)h[0] | ((unsigned)h[1] << 16);
        w[1] = (unsigned)h[2] | ((unsigned)h[3] << 16);
        *reinterpret_cast<uint2v*>(&Ab[s & 1][arow][awr_sh]) = w;
    };
    auto issueB = [&](int s) {
#pragma unroll
        for (int j = 0; j < 4; ++j) {
            int colb = wv * 64 + j * 16;
            const unsigned short* src =
                Btp + (size_t)(colb + bcf) * 512 + s * 32 + bg * 8;
            gload16(src, &Bb[s & 1][colb][0]);
        }
    };

    // ---- prologue ----
    loadA(0);
    issueB(0);
    WAITV(4);            // A(0) regs landed; B(0)'s 4 in flight
    writeA(0);
    WAITL(); WAITV(0);   // A ds_write + B gloads complete
    __builtin_amdgcn_s_barrier();

    // ---- 16 K-steps, ping-pong, 1 barrier per step ----
#pragma unroll
    for (int s = 0; s < 16; ++s) {
        if (s < 15) { loadA(s + 1); issueB(s + 1); }

        bf16x8 af[4], bf[4];
#pragma unroll
        for (int mi = 0; mi < 4; ++mi)
            af[mi] = *reinterpret_cast<const bf16x8*>(
                &Ab[s & 1][mi * 16 + rA][sl]);
#pragma unroll
        for (int ni = 0; ni < 4; ++ni)
            bf[ni] = *reinterpret_cast<const bf16x8*>(
                &Bb[s & 1][wv * 64 + ni * 16 + rA][sl]);
        WAITL();
        __builtin_amdgcn_sched_barrier(0);
        __builtin_amdgcn_s_setprio(1);
#pragma unroll
        for (int mi = 0; mi < 4; ++mi)
#pragma unroll
            for (int ni = 0; ni < 4; ++ni)
                acc[mi][ni] = __builtin_amdgcn_mfma_f32_16x16x32_bf16(
                    af[mi], bf[ni], acc[mi][ni], 0, 0, 0);
        __builtin_amdgcn_s_setprio(0);

        if (s < 15) {
            WAITV(4);            // A(s+1) regs landed (B(s+1) stays in flight)
            writeA(s + 1);
            WAITL(); WAITV(0);   // publish ds_write; B(s+1) in LDS
            __builtin_amdgcn_s_barrier();
        }
    }

    // ---- epilogue: C/D layout col=lane&15, row=(lane>>4)*4+rr ----
    const int orow_q = (lane >> 4) * 4;
#pragma unroll
    for (int mi = 0; mi < 4; ++mi) {
#pragma unroll
        for (int ni = 0; ni < 4; ++ni) {
            int col = wv * 64 + ni * 16 + rA;
            float bz = f32g ? ((const float*)biasp)[col]
                            : b2f(((const unsigned short*)biasp)[col]);
            long long rbase = row0 + mi * 16 + orow_q;
#pragma unroll
            for (int rr = 0; rr < 4; ++rr) {
                float v = acc[mi][ni][rr] + bz;
                if (MISH) v = mish_fast(v);
                long long oi = (rbase + rr) * opitch + col;
                if (OUTF32) ((float*)outp)[oi] = v;
                else        ((unsigned short*)outp)[oi] = f2b(v);
            }
        }
    }
}

// ---------------------------------------------------------------------------
// Pass A: raw scores, kp read EXACTLY ONCE (verified rounds 6-11).
// ---------------------------------------------------------------------------
__global__ __launch_bounds__(256)
void score_kernel(const unsigned short* __restrict__ q,
                  const unsigned short* __restrict__ kp,
                  float* __restrict__ outS,
                  float* __restrict__ inS)
{
    const int bid = blockIdx.x;            // 512 blocks
    const int b  = bid >> 5;
    const int i0 = ((bid >> 2) & 7) * 8;
    const int j0 = (bid & 3) * 16;
    const int t = threadIdx.x, lane = t & 63, wv = t >> 6;

    __shared__ alignas(16) unsigned short qs[24][512];
    __shared__ float souts[8][16][8];
    __shared__ float sins[16][8][8];

#pragma unroll
    for (int r8 = 0; r8 < 6; ++r8) {
        int r = wv * 6 + r8;
        int grow = (r < 8) ? (i0 + r) : (j0 + r - 8);
        gload16(q + ((long long)(b * 64 + grow)) * 512 + lane * 8, &qs[r][0]);
    }
    __syncthreads();

    for (int batch = 0; batch < 4; ++batch) {
        const int rbase = wv * 32 + batch * 8;
        short8 kv[8];
#pragma unroll
        for (int u = 0; u < 8; ++u) {
            int r = rbase + u;
            int ii = r >> 4, jj = r & 15;
            kv[u] = *reinterpret_cast<const short8*>(
                kp + ((long long)((b * 64 + i0 + ii) * 64) + j0 + jj) * 1024 + lane * 8);
        }
#pragma unroll
        for (int u = 0; u < 8; ++u) {
            int r = rbase + u;
            int ii = r >> 4, jj = r & 15;
            short8 qi = *reinterpret_cast<const short8*>(&qs[ii][lane * 8]);
            short8 qj = *reinterpret_cast<const short8*>(&qs[8 + jj][lane * 8]);
            float so = 0.f, si = 0.f;
#pragma unroll
            for (int e = 0; e < 8; ++e) {
                float kf = b2f((unsigned short)kv[u][e]);
                so += kf * b2f((unsigned short)qi[e]);
                si += kf * b2f((unsigned short)qj[e]);
            }
#pragma unroll
            for (int off = 1; off < 8; off <<= 1) {
                so += __shfl_xor(so, off);
                si += __shfl_xor(si, off);
            }
            if ((lane & 7) == 0) {
                souts[ii][jj][lane >> 3] = so * 0.125f;
                sins[jj][ii][lane >> 3]  = si * 0.125f;
            }
        }
    }
    __syncthreads();

    {
        int h  = t >> 5;
        int ii = (t >> 2) & 7;
        int qq = t & 3;
        f32x4 v;
#pragma unroll
        for (int e = 0; e < 4; ++e) v[e] = souts[ii][qq * 4 + e][h];
        *reinterpret_cast<f32x4*>(
            &outS[(((long long)(b * 8 + h) * 64) + i0 + ii) * 64 + j0 + qq * 4]) = v;
    }
    {
        int h  = t >> 5;
        int jj = (t >> 1) & 15;
        int hf = t & 1;
        f32x4 v;
#pragma unroll
        for (int e = 0; e < 4; ++e) v[e] = sins[jj][hf * 4 + e][h];
        *reinterpret_cast<f32x4*>(
            &inS[(((long long)(b * 8 + h) * 64) + j0 + jj) * 64 + i0 + hf * 4]) = v;
    }
}

// ---------------------------------------------------------------------------
__global__ __launch_bounds__(256)
void softmax_combine(float* __restrict__ outS, const float* __restrict__ inS)
{
    const long long row = (long long)blockIdx.x * 4 + (threadIdx.x >> 6);
    const int l = threadIdx.x & 63;
    const int x = (int)(row & 63);
    float so = outS[row * 64 + l];
    float si = inS[row * 64 + l];
    float mo = so, mi = si;
    for (int off = 32; off; off >>= 1) {
        mo = fmaxf(mo, __shfl_xor(mo, off));
        mi = fmaxf(mi, __shfl_xor(mi, off));
    }
    float eo = __expf(so - mo), ei = __expf(si - mi);
    float zo = eo, zi = ei;
    for (int off = 32; off; off >>= 1) {
        zo += __shfl_xor(zo, off);
        zi += __shfl_xor(zi, off);
    }
    float ao = eo / zo, ai = ei / zi;
    outS[row * 64 + l] = (l == x) ? ai : (ao + ai);
}

// ---------------------------------------------------------------------------
__global__ __launch_bounds__(512)
void nh_kernel(const float* __restrict__ msg,
               const unsigned short* __restrict__ v,
               unsigned short* __restrict__ nh)
{
    const int bm = blockIdx.x;
    const int b = bm >> 6, m = bm & 63;
    const int t = threadIdx.x;
    __shared__ float ms2[8 * 64];
    ms2[t] = msg[((long long)b * 8 + (t >> 6)) * 4096 + m * 64 + (t & 63)];
    __syncthreads();
    const float* mrow = &ms2[(t >> 6) * 64];
    float acc = 0.f;
#pragma unroll 8
    for (int n = 0; n < 64; ++n)
        acc += mrow[n] * b2f(v[((long long)b * 64 + n) * 512 + t]);
    nh[(long long)bm * 1024 + t] = f2b(acc);
}

// ---------------------------------------------------------------------------
extern "C" void kernel_launch(void* const* d_in, const int* in_sizes, int n_in,
                              void* d_out, int out_size, void* d_ws, size_t ws_size,
                              hipStream_t stream)
{
    const void* qn = d_in[0];
    const void* vn = d_in[1];
    const void* ke = d_in[2];
    const unsigned* adj = (const unsigned*)d_in[3];
    const void* Wq = d_in[4];  const void* bq = d_in[5];
    const void* Wk = d_in[6];  const void* bk = d_in[7];
    const void* Wv = d_in[8];  const void* bv = d_in[9];
    const void* Wn = d_in[10]; const void* bn = d_in[11];
    const void* We = d_in[12]; const void* be = d_in[13];

    float* out_node = (float*)d_out;                       // 16*64*512 f32 (2 MB)
    float* out_edge = out_node + (size_t)NB * NN * ND;     // 16*64*64*512 f32
    unsigned short* kp = (unsigned short*)out_edge;        // bf16, pitch 1024 shorts
    unsigned short* nh = (unsigned short*)out_node;        // bf16, pitch 1024 shorts
    float* inS = out_node;  // in-scores scratch (2 MB) — dead before nh_kernel

    char* wsb = (char*)d_ws;
    int* flag = (int*)wsb;
    unsigned short* Wt  = (unsigned short*)(wsb + 16);     // 5 x 512 KB
    unsigned short* Wqt = Wt + 0 * 262144;
    unsigned short* Wkt = Wt + 1 * 262144;
    unsigned short* Wvt = Wt + 2 * 262144;
    unsigned short* Wnt = Wt + 3 * 262144;
    unsigned short* Wet = Wt + 4 * 262144;
    unsigned short* q_ws = Wt + 5 * 262144;                // 1 MB bf16
    unsigned short* v_ws = q_ws + 524288;                  // 1 MB bf16
    float* msg = (float*)(v_ws + 524288);                  // 2 MB f32
    // ws total ~6.5 MB

    probe_dtype<<<1, 64, 0, stream>>>(adj, flag);
    wtrans<<<dim3(8, 8, 5), 256, 0, stream>>>(Wq, Wk, Wv, Wn, We, Wt, flag);
    // q + v projections merged (f32 A): blocks 0-15 -> q, 16-31 -> v
    gemm9<0, false, false><<<32, 512, 0, stream>>>(
        qn, 512, Wqt, bq, nullptr, q_ws, 512, flag, vn, Wvt, bv, v_ws);
    // k projection -> strided bf16 inside the edge f32 output region
    gemm9<0, false, false><<<1024, 512, 0, stream>>>(
        ke, 512, Wkt, bk, nullptr, kp, 1024, flag, nullptr, nullptr, nullptr, nullptr);
    // message: raw scores (kp read once) + softmax/combine
    score_kernel<<<512, 256, 0, stream>>>(q_ws, kp, msg, inS);
    softmax_combine<<<2048, 256, 0, stream>>>(msg, inS);
    // node path
    nh_kernel<<<NB * NN, 512, 0, stream>>>(msg, v_ws, nh);
    gemm9<1, true, true><<<16, 512, 0, stream>>>(
        nh, 1024, Wnt, bn, nullptr, out_node, 512, flag, nullptr, nullptr, nullptr, nullptr);
    // edge path: msg-scaling fused into A-staging; in-place
    gemm9<2, true, true><<<1024, 512, 0, stream>>>(
        kp, 1024, Wet, be, msg, out_edge, 512, flag, nullptr, nullptr, nullptr, nullptr);
}

// Round 13
// 198.410 us; speedup vs baseline: 1.8213x; 1.3113x over previous
//
#include <hip/hip_runtime.h>

#define DEV __device__ __forceinline__

typedef __attribute__((ext_vector_type(8))) short short8;
typedef __bf16 bf16x8 __attribute__((ext_vector_type(8)));
typedef __attribute__((ext_vector_type(4))) float f32x4;

constexpr int NB = 16;
constexpr int NN = 64;
constexpr int ND = 512;
constexpr int NH = 8;

DEV float b2f(unsigned short h) { return __uint_as_float(((unsigned)h) << 16); }
DEV unsigned short f2b(float f) {
    unsigned u = __float_as_uint(f);
    return (unsigned short)((u + 0x7fffu + ((u >> 16) & 1u)) >> 16);
}
// mish(x) = x*(t^2+2t)/(t^2+2t+2), t=e^x; x>15 -> x
DEV float mish_fast(float x) {
    float t = __expf(x);
    float w = t * (t + 2.0f);
    float r = x * w * __builtin_amdgcn_rcpf(w + 2.0f);
    return (x > 15.0f) ? x : r;
}
DEV void gload16(const unsigned short* g, unsigned short* lds) {
    __builtin_amdgcn_global_load_lds((const __attribute__((address_space(1))) void*)g,
                                     (__attribute__((address_space(3))) void*)lds,
                                     16, 0, 0);
}

// ---------------------------------------------------------------------------
__global__ __launch_bounds__(64)
void probe_dtype(const unsigned* __restrict__ adj, int* __restrict__ flag)
{
    int t = threadIdx.x;
    int c = 0;
#pragma unroll
    for (int i = 0; i < 4; ++i) c += (int)((adj[t * 4 + i] >> 15) & 1u);
    for (int off = 32; off; off >>= 1) c += __shfl_xor(c, off);
    if (t == 0) flag[0] = (c > 32) ? 1 : 0;
}

// ---------------------------------------------------------------------------
// Transpose the five 512x512 weights into FRAG-MAJOR bf16:
//   Wt2[ (k>>5)*16384 + c*32 + (k&31) ] = W[k][c]
// so that a wave's MFMA B-fragment (16 cols x 1 k-step, lane=(col,p)) is one
// fully-contiguous 1 KB load: addr = s*16384 + col0*32 + rA*32 + p*8.
// ---------------------------------------------------------------------------
__global__ __launch_bounds__(256)
void wtrans2(const void* W0, const void* W1, const void* W2, const void* W3,
             const void* W4, unsigned short* __restrict__ out,
             const int* __restrict__ flag)
{
    const void* W = (blockIdx.z == 0) ? W0 : (blockIdx.z == 1) ? W1 :
                    (blockIdx.z == 2) ? W2 : (blockIdx.z == 3) ? W3 : W4;
    const int f32 = flag[0];
    unsigned short* o = out + (size_t)blockIdx.z * 262144;
    __shared__ unsigned short tile[64][65];
    const int t = threadIdx.x;
    const int k0 = blockIdx.x * 64, c0 = blockIdx.y * 64;
#pragma unroll
    for (int rep = 0; rep < 16; ++rep) {
        int idx = rep * 256 + t;
        int r = idx >> 6, c = idx & 63;         // k-fine, c-fine
        size_t gi = (size_t)(k0 + r) * 512 + c0 + c;
        float v = f32 ? ((const float*)W)[gi]
                      : b2f(((const unsigned short*)W)[gi]);
        tile[r][c] = f2b(v);
    }
    __syncthreads();
#pragma unroll
    for (int rep = 0; rep < 16; ++rep) {
        int idx = rep * 256 + t;
        int cc = idx >> 6, kk = idx & 63;       // kk fast -> contiguous (k&31)
        int k = k0 + kk;
        o[(size_t)(k >> 5) * 16384 + (size_t)(c0 + cc) * 32 + (k & 31)] = tile[kk][cc];
    }
}

// ---------------------------------------------------------------------------
// GEMM v10: out[64 x 512 per block] = f( A[64 x 512] @ W + bias )
// BARRIER-FREE K-loop, NO B-LDS:
//  - A staged ONCE into 64 KB LDS (bf16, granule slot g^(r&7); frag reads are
//    2-way bank-aliased = free). f32 cvt / msg-scale folded into staging.
//    One __syncthreads() after staging; nothing else.
//  - B read straight global->VGPR from frag-major Wt2 (L2-resident 512 KB):
//    per wave-step, 4 fully-contiguous 1 KB dwordx4 loads (no duplication:
//    wave wv owns cols [wv*64,+64)). Compiler inserts exact waitcnts and
//    pipelines; waves drift freely (no cross-wave coupling at all).
// 512 thr / 8 waves, wave tile 64x64 (acc[4][4] = 64 VGPR, total ~115 -> 4
// waves/SIMD at launch_bounds(512,4)); LDS 64 KB -> 2 blocks/CU.
// AMODE: 0 = raw input (f32 per flag / bf16), 1 = bf16, 2 = bf16 * msg.
// In-place safe: ALL global A reads precede the staging barrier; epilogue
// writes after the K-loop; blocks own disjoint 64-row ranges.
// ---------------------------------------------------------------------------
template<int AMODE, bool MISH, bool OUTF32>
__global__ __launch_bounds__(512, 4)
void gemm10(const void* A, long long apitch,
            const unsigned short* __restrict__ Bt2,
            const void* __restrict__ bias_raw,
            const float* __restrict__ msg,
            void* out, long long opitch,
            const int* __restrict__ flag,
            const void* A2, const unsigned short* Bt2b,
            const void* bias2, void* out2)
{
    __shared__ alignas(16) unsigned short As[64][512];   // 64 KB
    const int f32g = flag[0];
    const int t = threadIdx.x;
    const int lane = t & 63;
    const int wv = t >> 6;           // 0..7 = 64-col panel

    long long row0;
    const void* Ap = A; const unsigned short* Btp = Bt2;
    const void* biasp = bias_raw; void* outp = out;
    if (A2 != nullptr && (int)blockIdx.x >= (int)(gridDim.x >> 1)) {
        Ap = A2; Btp = Bt2b; biasp = bias2; outp = out2;
        row0 = (long long)(blockIdx.x - (gridDim.x >> 1)) * 64;
    } else {
        row0 = (long long)blockIdx.x * 64;
    }

    // ---- stage the whole A panel once (64 rows x 512 k, swizzled bf16) ----
    {
        const int r = t >> 3;            // row 0..63
        const int q = t & 7;             // granule phase 0..7
        const long long gr = row0 + r;
        const float* mrow = nullptr;
        if (AMODE == 2) {
            int b = (int)(gr >> 12), m = (int)(gr >> 6) & 63, n = (int)gr & 63;
            mrow = msg + (((long long)b * 8) * 64 + m) * 64 + n;   // + head*4096
        }
        if (AMODE == 0 && f32g) {
            const float* Af = (const float*)Ap + gr * apitch;
#pragma unroll
            for (int i = 0; i < 8; ++i) {
                int g = q + 8 * i;       // granule 0..63; head = g>>3 = i
                f32x4 x0 = *reinterpret_cast<const f32x4*>(Af + g * 8);
                f32x4 x1 = *reinterpret_cast<const f32x4*>(Af + g * 8 + 4);
                short8 sv;
#pragma unroll
                for (int j = 0; j < 4; ++j) {
                    sv[j]     = (short)f2b(x0[j]);
                    sv[j + 4] = (short)f2b(x1[j]);
                }
                *reinterpret_cast<short8*>(&As[r][(g ^ (r & 7)) * 8]) = sv;
            }
        } else {
            const unsigned short* Ah = (const unsigned short*)Ap + gr * apitch;
#pragma unroll
            for (int i = 0; i < 8; ++i) {
                int g = q + 8 * i;
                short8 v = *reinterpret_cast<const short8*>(Ah + g * 8);
                if (AMODE == 2) {
                    float sc = mrow[i * 4096];          // head = i
#pragma unroll
                    for (int j = 0; j < 8; ++j)
                        v[j] = (short)f2b(b2f((unsigned short)v[j]) * sc);
                }
                *reinterpret_cast<short8*>(&As[r][(g ^ (r & 7)) * 8]) = v;
            }
        }
    }
    __syncthreads();      // the ONLY synchronization in this kernel

    const int rA = lane & 15;
    const int p  = lane >> 4;
    // frag-major B: wave wv, frag ni, step s -> 1 KB contiguous at
    //   Btp + s*16384 + (wv*64 + ni*16)*32 + rA*32 + p*8
    const unsigned short* bbase = Btp + ((size_t)(wv * 64 + rA) * 32 + p * 8);

    f32x4 acc[4][4];
#pragma unroll
    for (int mi = 0; mi < 4; ++mi)
#pragma unroll
        for (int ni = 0; ni < 4; ++ni) acc[mi][ni] = f32x4{0.f, 0.f, 0.f, 0.f};

#pragma unroll
    for (int s = 0; s < 16; ++s) {
        bf16x8 bf[4], af[4];
#pragma unroll
        for (int ni = 0; ni < 4; ++ni)
            bf[ni] = *reinterpret_cast<const bf16x8*>(bbase + (size_t)s * 16384 + ni * 512);
#pragma unroll
        for (int mi = 0; mi < 4; ++mi)
            af[mi] = *reinterpret_cast<const bf16x8*>(
                &As[mi * 16 + rA][((((s << 2) | p)) ^ (rA & 7)) << 3]);
#pragma unroll
        for (int mi = 0; mi < 4; ++mi)
#pragma unroll
            for (int ni = 0; ni < 4; ++ni)
                acc[mi][ni] = __builtin_amdgcn_mfma_f32_16x16x32_bf16(
                    af[mi], bf[ni], acc[mi][ni], 0, 0, 0);
    }

    // ---- epilogue: C/D layout col=lane&15, row=(lane>>4)*4+rr ----
    const int orow_q = (lane >> 4) * 4;
#pragma unroll
    for (int mi = 0; mi < 4; ++mi) {
#pragma unroll
        for (int ni = 0; ni < 4; ++ni) {
            int col = wv * 64 + ni * 16 + rA;
            float bz = f32g ? ((const float*)biasp)[col]
                            : b2f(((const unsigned short*)biasp)[col]);
            long long rbase = row0 + mi * 16 + orow_q;
#pragma unroll
            for (int rr = 0; rr < 4; ++rr) {
                float v = acc[mi][ni][rr] + bz;
                if (MISH) v = mish_fast(v);
                long long oi = (rbase + rr) * opitch + col;
                if (OUTF32) ((float*)outp)[oi] = v;
                else        ((unsigned short*)outp)[oi] = f2b(v);
            }
        }
    }
}

// ---------------------------------------------------------------------------
// Pass A: raw scores, kp read EXACTLY ONCE (verified rounds 6-12).
// ---------------------------------------------------------------------------
__global__ __launch_bounds__(256)
void score_kernel(const unsigned short* __restrict__ q,
                  const unsigned short* __restrict__ kp,
                  float* __restrict__ outS,
                  float* __restrict__ inS)
{
    const int bid = blockIdx.x;            // 512 blocks
    const int b  = bid >> 5;
    const int i0 = ((bid >> 2) & 7) * 8;
    const int j0 = (bid & 3) * 16;
    const int t = threadIdx.x, lane = t & 63, wv = t >> 6;

    __shared__ alignas(16) unsigned short qs[24][512];
    __shared__ float souts[8][16][8];
    __shared__ float sins[16][8][8];

#pragma unroll
    for (int r8 = 0; r8 < 6; ++r8) {
        int r = wv * 6 + r8;
        int grow = (r < 8) ? (i0 + r) : (j0 + r - 8);
        gload16(q + ((long long)(b * 64 + grow)) * 512 + lane * 8, &qs[r][0]);
    }
    __syncthreads();

    for (int batch = 0; batch < 4; ++batch) {
        const int rbase = wv * 32 + batch * 8;
        short8 kv[8];
#pragma unroll
        for (int u = 0; u < 8; ++u) {
            int r = rbase + u;
            int ii = r >> 4, jj = r & 15;
            kv[u] = *reinterpret_cast<const short8*>(
                kp + ((long long)((b * 64 + i0 + ii) * 64) + j0 + jj) * 1024 + lane * 8);
        }
#pragma unroll
        for (int u = 0; u < 8; ++u) {
            int r = rbase + u;
            int ii = r >> 4, jj = r & 15;
            short8 qi = *reinterpret_cast<const short8*>(&qs[ii][lane * 8]);
            short8 qj = *reinterpret_cast<const short8*>(&qs[8 + jj][lane * 8]);
            float so = 0.f, si = 0.f;
#pragma unroll
            for (int e = 0; e < 8; ++e) {
                float kf = b2f((unsigned short)kv[u][e]);
                so += kf * b2f((unsigned short)qi[e]);
                si += kf * b2f((unsigned short)qj[e]);
            }
#pragma unroll
            for (int off = 1; off < 8; off <<= 1) {
                so += __shfl_xor(so, off);
                si += __shfl_xor(si, off);
            }
            if ((lane & 7) == 0) {
                souts[ii][jj][lane >> 3] = so * 0.125f;
                sins[jj][ii][lane >> 3]  = si * 0.125f;
            }
        }
    }
    __syncthreads();

    {
        int h  = t >> 5;
        int ii = (t >> 2) & 7;
        int qq = t & 3;
        f32x4 v;
#pragma unroll
        for (int e = 0; e < 4; ++e) v[e] = souts[ii][qq * 4 + e][h];
        *reinterpret_cast<f32x4*>(
            &outS[(((long long)(b * 8 + h) * 64) + i0 + ii) * 64 + j0 + qq * 4]) = v;
    }
    {
        int h  = t >> 5;
        int jj = (t >> 1) & 15;
        int hf = t & 1;
        f32x4 v;
#pragma unroll
        for (int e = 0; e < 4; ++e) v[e] = sins[jj][hf * 4 + e][h];
        *reinterpret_cast<f32x4*>(
            &inS[(((long long)(b * 8 + h) * 64) + j0 + jj) * 64 + i0 + hf * 4]) = v;
    }
}

// ---------------------------------------------------------------------------
__global__ __launch_bounds__(256)
void softmax_combine(float* __restrict__ outS, const float* __restrict__ inS)
{
    const long long row = (long long)blockIdx.x * 4 + (threadIdx.x >> 6);
    const int l = threadIdx.x & 63;
    const int x = (int)(row & 63);
    float so = outS[row * 64 + l];
    float si = inS[row * 64 + l];
    float mo = so, mi = si;
    for (int off = 32; off; off >>= 1) {
        mo = fmaxf(mo, __shfl_xor(mo, off));
        mi = fmaxf(mi, __shfl_xor(mi, off));
    }
    float eo = __expf(so - mo), ei = __expf(si - mi);
    float zo = eo, zi = ei;
    for (int off = 32; off; off >>= 1) {
        zo += __shfl_xor(zo, off);
        zi += __shfl_xor(zi, off);
    }
    float ao = eo / zo, ai = ei / zi;
    outS[row * 64 + l] = (l == x) ? ai : (ao + ai);
}

// ---------------------------------------------------------------------------
__global__ __launch_bounds__(512)
void nh_kernel(const float* __restrict__ msg,
               const unsigned short* __restrict__ v,
               unsigned short* __restrict__ nh)
{
    const int bm = blockIdx.x;
    const int b = bm >> 6, m = bm & 63;
    const int t = threadIdx.x;
    __shared__ float ms2[8 * 64];
    ms2[t] = msg[((long long)b * 8 + (t >> 6)) * 4096 + m * 64 + (t & 63)];
    __syncthreads();
    const float* mrow = &ms2[(t >> 6) * 64];
    float acc = 0.f;
#pragma unroll 8
    for (int n = 0; n < 64; ++n)
        acc += mrow[n] * b2f(v[((long long)b * 64 + n) * 512 + t]);
    nh[(long long)bm * 1024 + t] = f2b(acc);
}

// ---------------------------------------------------------------------------
extern "C" void kernel_launch(void* const* d_in, const int* in_sizes, int n_in,
                              void* d_out, int out_size, void* d_ws, size_t ws_size,
                              hipStream_t stream)
{
    const void* qn = d_in[0];
    const void* vn = d_in[1];
    const void* ke = d_in[2];
    const unsigned* adj = (const unsigned*)d_in[3];
    const void* Wq = d_in[4];  const void* bq = d_in[5];
    const void* Wk = d_in[6];  const void* bk = d_in[7];
    const void* Wv = d_in[8];  const void* bv = d_in[9];
    const void* Wn = d_in[10]; const void* bn = d_in[11];
    const void* We = d_in[12]; const void* be = d_in[13];

    float* out_node = (float*)d_out;                       // 16*64*512 f32 (2 MB)
    float* out_edge = out_node + (size_t)NB * NN * ND;     // 16*64*64*512 f32
    unsigned short* kp = (unsigned short*)out_edge;        // bf16, pitch 1024 shorts
    unsigned short* nh = (unsigned short*)out_node;        // bf16, pitch 1024 shorts
    float* inS = out_node;  // in-scores scratch (2 MB) — dead before nh_kernel

    char* wsb = (char*)d_ws;
    int* flag = (int*)wsb;
    unsigned short* Wt  = (unsigned short*)(wsb + 16);     // 5 x 512 KB (frag-major)
    unsigned short* Wqt = Wt + 0 * 262144;
    unsigned short* Wkt = Wt + 1 * 262144;
    unsigned short* Wvt = Wt + 2 * 262144;
    unsigned short* Wnt = Wt + 3 * 262144;
    unsigned short* Wet = Wt + 4 * 262144;
    unsigned short* q_ws = Wt + 5 * 262144;                // 1 MB bf16
    unsigned short* v_ws = q_ws + 524288;                  // 1 MB bf16
    float* msg = (float*)(v_ws + 524288);                  // 2 MB f32
    // ws total ~6.5 MB

    probe_dtype<<<1, 64, 0, stream>>>(adj, flag);
    wtrans2<<<dim3(8, 8, 5), 256, 0, stream>>>(Wq, Wk, Wv, Wn, We, Wt, flag);
    // q + v projections merged (f32 A): blocks 0-15 -> q, 16-31 -> v
    gemm10<0, false, false><<<32, 512, 0, stream>>>(
        qn, 512, Wqt, bq, nullptr, q_ws, 512, flag, vn, Wvt, bv, v_ws);
    // k projection -> strided bf16 inside the edge f32 output region
    gemm10<0, false, false><<<1024, 512, 0, stream>>>(
        ke, 512, Wkt, bk, nullptr, kp, 1024, flag, nullptr, nullptr, nullptr, nullptr);
    // message: raw scores (kp read once) + softmax/combine
    score_kernel<<<512, 256, 0, stream>>>(q_ws, kp, msg, inS);
    softmax_combine<<<2048, 256, 0, stream>>>(msg, inS);
    // node path
    nh_kernel<<<NB * NN, 512, 0, stream>>>(msg, v_ws, nh);
    gemm10<1, true, true><<<16, 512, 0, stream>>>(
        nh, 1024, Wnt, bn, nullptr, out_node, 512, flag, nullptr, nullptr, nullptr, nullptr);
    // edge path: msg-scaling fused into A-staging; in-place
    gemm10<2, true, true><<<1024, 512, 0, stream>>>(
        kp, 1024, Wet, be, msg, out_edge, 512, flag, nullptr, nullptr, nullptr, nullptr);
}